// Round 3
// baseline (816.645 us; speedup 1.0000x reference)
//
#include <hip/hip_runtime.h>

#define Nn 40000
#define Ee 600000
#define Hh 128
#define Gg 32
#define Cc 6

typedef unsigned int u32;

// ---------------- CSR build ----------------
__global__ __launch_bounds__(256) void k_init(int* counts, float* emb, int* gcnt) {
    int i = blockIdx.x * 256 + threadIdx.x;
    if (i < Nn) counts[i] = 0;
    if (i < Gg * Hh) emb[i] = 0.f;
    if (i < Gg) gcnt[i] = 0;
}

__global__ __launch_bounds__(256) void k_count(const int* __restrict__ dst, int* __restrict__ counts) {
    int i = blockIdx.x * 256 + threadIdx.x;
    if (i < Ee) atomicAdd(&counts[dst[i]], 1);
}

// NOTE: counts and cursor ALIAS (cursor overwrites counts after its last read) — no __restrict__.
__global__ __launch_bounds__(1024) void k_scan(const int* counts, int* row_ptr,
                                               int* cursor, float* dinv) {
    __shared__ int sm[1024];
    int t = threadIdx.x;
    const int CH = (Nn + 1023) / 1024;  // 40
    int base = t * CH;
    int s = 0;
    for (int i = 0; i < CH; i++) { int idx = base + i; if (idx < Nn) s += counts[idx]; }
    sm[t] = s;
    __syncthreads();
    for (int ofs = 1; ofs < 1024; ofs <<= 1) {
        int v = (t >= ofs) ? sm[t - ofs] : 0;
        __syncthreads();
        sm[t] += v;
        __syncthreads();
    }
    int run = sm[t] - s;  // exclusive prefix of this thread's chunk
    for (int i = 0; i < CH; i++) {
        int idx = base + i;
        if (idx < Nn) {
            int c = counts[idx];          // read BEFORE aliased cursor write
            row_ptr[idx] = run;
            cursor[idx] = run;
            dinv[idx] = rsqrtf((float)(c + 1));
            run += c;
        }
    }
    if (t == 1023) row_ptr[Nn] = sm[1023];
}

__global__ __launch_bounds__(256) void k_scatter(const int* __restrict__ src, const int* __restrict__ dst,
                                                 int* __restrict__ cursor, int* __restrict__ colidx) {
    int i = blockIdx.x * 256 + threadIdx.x;
    if (i < Ee) {
        int d = dst[i];
        int p = atomicAdd(&cursor[d], 1);
        if ((u32)p < (u32)Ee) colidx[p] = src[i];
    }
}

// ---------------- aggregations (wave per node), f32 ----------------
__global__ __launch_bounds__(256) void k_agg_plain(const float* __restrict__ in, float* __restrict__ out,
                                                   const int* __restrict__ row_ptr, const int* __restrict__ colidx) {
    int wid = threadIdx.x >> 6, lane = threadIdx.x & 63;
    int node = blockIdx.x * 4 + wid;
    int beg = row_ptr[node], end = row_ptr[node + 1];
    float ax = 0.f, ay = 0.f;
    for (int e = beg; e < end; ++e) {
        int s = colidx[e];
        float2 v = *(const float2*)(in + (size_t)s * 128 + lane * 2);
        ax += v.x; ay += v.y;
    }
    float2 o = { ax, ay };
    *(float2*)(out + (size_t)node * 128 + lane * 2) = o;
}

// GCN normalized aggregation incl. self-loop: out_i = di*sum_s ds*in_s + di^2*in_i
__global__ __launch_bounds__(256) void k_agg_gcn(const float* __restrict__ in, float* __restrict__ out,
                                                 const int* __restrict__ row_ptr, const int* __restrict__ colidx,
                                                 const float* __restrict__ dinv) {
    int wid = threadIdx.x >> 6, lane = threadIdx.x & 63;
    int node = blockIdx.x * 4 + wid;
    int beg = row_ptr[node], end = row_ptr[node + 1];
    float di = dinv[node];
    float ax = 0.f, ay = 0.f;
    for (int e = beg; e < end; ++e) {
        int s = colidx[e];
        float ds = dinv[s];
        float2 v = *(const float2*)(in + (size_t)s * 128 + lane * 2);
        ax += ds * v.x; ay += ds * v.y;
    }
    float2 vs = *(const float2*)(in + (size_t)node * 128 + lane * 2);
    float d2 = di * di;
    float2 o = { di * ax + d2 * vs.x, di * ay + d2 * vs.y };
    *(float2*)(out + (size_t)node * 128 + lane * 2) = o;
}

// ---------------- f32 GEMM: C = [relu]( A1@B1 [+ A2@B2] + bias ), M=40000, K=N=128 ----------------
// Block: 32 rows x 128 cols; B staged in 64 KB LDS; A read as wave-uniform float4 broadcasts.
// C may alias A1 (in-place, layer 2): each block reads only its own 32 rows before writing them.
__global__ __launch_bounds__(256) void k_gemm(const float* A1, const float* __restrict__ B1,
                                              const float* A2, const float* __restrict__ B2,
                                              const float* __restrict__ bias, float* C,
                                              int dual, int relu) {
    __shared__ float Bs[128 * 128];
    int t = threadIdx.x;
    int m0 = blockIdx.x * 32 + (t >> 5) * 4;   // 4 rows per thread
    int n0 = (t & 31) * 4;                     // 4 cols per thread
    float acc[4][4] = {};
    const float* Asrc = A1;
    const float* Bsrc = B1;
    int passes = dual ? 2 : 1;
    for (int pass = 0; pass < passes; ++pass) {
        __syncthreads();   // protect Bs reuse across passes (no-op cost on pass 0)
#pragma unroll
        for (int i = 0; i < 16; ++i) {
            int idx = i * 1024 + t * 4;
            *(float4*)&Bs[idx] = *(const float4*)&Bsrc[idx];
        }
        __syncthreads();
        for (int kb = 0; kb < 8; ++kb) {
            float af[4][16];
#pragma unroll
            for (int r = 0; r < 4; ++r)
#pragma unroll
                for (int q = 0; q < 4; ++q)
                    *(float4*)&af[r][q * 4] =
                        *(const float4*)&Asrc[(size_t)(m0 + r) * 128 + kb * 16 + q * 4];
#pragma unroll
            for (int j = 0; j < 16; ++j) {
                float4 b = *(const float4*)&Bs[(kb * 16 + j) * 128 + n0];
#pragma unroll
                for (int r = 0; r < 4; ++r) {
                    acc[r][0] += af[r][j] * b.x;
                    acc[r][1] += af[r][j] * b.y;
                    acc[r][2] += af[r][j] * b.z;
                    acc[r][3] += af[r][j] * b.w;
                }
            }
        }
        Asrc = A2; Bsrc = B2;
    }
#pragma unroll
    for (int r = 0; r < 4; ++r) {
        float4 v;
        float* vp = &v.x;
#pragma unroll
        for (int c = 0; c < 4; ++c) {
            float x = acc[r][c] + bias[n0 + c];
            vp[c] = relu ? fmaxf(x, 0.f) : x;
        }
        *(float4*)&C[(size_t)(m0 + r) * 128 + n0] = v;
    }
}

// ---------------- mean-pool (batch is sorted) ----------------
__global__ __launch_bounds__(128) void k_pool(const float* __restrict__ h, const int* __restrict__ batch,
                                              float* __restrict__ emb, int* __restrict__ gcnt) {
    int f = threadIdx.x;
    int base = blockIdx.x * 64;
    float acc = 0.f; int cnt = 0;
    int curg = batch[base];
    for (int i = 0; i < 64; i++) {
        int node = base + i;
        int g = batch[node];
        if (g != curg) {
            atomicAdd(&emb[curg * 128 + f], acc);
            if (f == 0) atomicAdd(&gcnt[curg], cnt);
            acc = 0.f; cnt = 0; curg = g;
        }
        acc += h[(size_t)node * 128 + f];
        cnt++;
    }
    atomicAdd(&emb[curg * 128 + f], acc);
    if (f == 0) atomicAdd(&gcnt[curg], cnt);
}

// ---------------- final: embedding + logits (f32 out) ----------------
__global__ __launch_bounds__(256) void k_final(const float* __restrict__ emb, const int* __restrict__ gcnt,
                                               const float* __restrict__ lw, const float* __restrict__ lb,
                                               float* __restrict__ out) {
    int t = threadIdx.x;
    for (int i = t; i < Gg * Hh; i += 256) {
        int g = i >> 7;
        float c = fmaxf((float)gcnt[g], 1.f);
        out[Gg * Cc + i] = emb[i] / c;
    }
    if (t < Gg * Cc) {
        int g = t / Cc, c = t % Cc;
        float cn = fmaxf((float)gcnt[g], 1.f);
        float s = lb[c];
        for (int f = 0; f < Hh; f++)
            s += (emb[g * 128 + f] / cn) * lw[f * Cc + c];
        out[t] = s;
    }
}

extern "C" void kernel_launch(void* const* d_in, const int* in_sizes, int n_in,
                              void* d_out, int out_size, void* d_ws, size_t ws_size,
                              hipStream_t stream) {
    const float* x       = (const float*)d_in[0];
    const int*   ei      = (const int*)d_in[1];
    const int*   batch   = (const int*)d_in[2];
    const float* w1_root = (const float*)d_in[3];
    const float* w1_rel  = (const float*)d_in[4];
    const float* b1      = (const float*)d_in[5];
    const float* w2_root = (const float*)d_in[6];
    const float* w2_rel  = (const float*)d_in[7];
    const float* b2      = (const float*)d_in[8];
    const float* w3      = (const float*)d_in[9];
    const float* b3      = (const float*)d_in[10];
    const float* w4      = (const float*)d_in[11];
    const float* b4      = (const float*)d_in[12];
    const float* w5      = (const float*)d_in[13];
    const float* b5      = (const float*)d_in[14];
    const float* lw      = (const float*)d_in[15];
    const float* lb      = (const float*)d_in[16];
    const int* srcp = ei;
    const int* dstp = ei + Ee;
    float* out = (float*)d_out;

    // ---- workspace layout (~44.3 MiB) ----
    char* w = (char*)d_ws;
    size_t off = 0;
    auto alloc = [&](size_t bytes) { size_t r = off; off += (bytes + 255) & ~(size_t)255; return r; };
    int*   counts  = (int*)(w + alloc(Nn * 4));          // doubles as scatter cursor
    int*   row_ptr = (int*)(w + alloc((Nn + 1) * 4));
    int*   colidx  = (int*)(w + alloc((size_t)Ee * 4));
    float* dinv    = (float*)(w + alloc(Nn * 4));
    float* emb     = (float*)(w + alloc(Gg * Hh * 4));
    int*   gcnt    = (int*)(w + alloc(Gg * 4));
    float* agg     = (float*)(w + alloc((size_t)Nn * Hh * 4));
    float* hA      = (float*)(w + alloc((size_t)Nn * Hh * 4));
    (void)ws_size;
    const float* nil = (const float*)nullptr;

    // CSR build
    hipLaunchKernelGGL(k_init, dim3(157), dim3(256), 0, stream, counts, emb, gcnt);
    hipLaunchKernelGGL(k_count, dim3((Ee + 255) / 256), dim3(256), 0, stream, dstp, counts);
    hipLaunchKernelGGL(k_scan, dim3(1), dim3(1024), 0, stream, counts, row_ptr, counts, dinv);
    hipLaunchKernelGGL(k_scatter, dim3((Ee + 255) / 256), dim3(256), 0, stream, srcp, dstp, counts, colidx);

    // layer 1 (GraphConv): hA = relu(x@w1_root + agg(x)@w1_rel + b1)
    hipLaunchKernelGGL(k_agg_plain, dim3(Nn / 4), dim3(256), 0, stream, x, agg, row_ptr, colidx);
    hipLaunchKernelGGL(k_gemm, dim3(Nn / 32), dim3(256), 0, stream, x, w1_root, agg, w1_rel, b1, hA, 1, 1);
    // layer 2 (GraphConv), GEMM in-place on hA
    hipLaunchKernelGGL(k_agg_plain, dim3(Nn / 4), dim3(256), 0, stream, hA, agg, row_ptr, colidx);
    hipLaunchKernelGGL(k_gemm, dim3(Nn / 32), dim3(256), 0, stream, hA, w2_root, agg, w2_rel, b2, hA, 1, 1);
    // layers 3..5 (GCNConv): agg = D^-1/2(A+I)D^-1/2 h ; h = [relu](agg@w + b)
    hipLaunchKernelGGL(k_agg_gcn, dim3(Nn / 4), dim3(256), 0, stream, hA, agg, row_ptr, colidx, dinv);
    hipLaunchKernelGGL(k_gemm, dim3(Nn / 32), dim3(256), 0, stream, agg, w3, nil, nil, b3, hA, 0, 1);
    hipLaunchKernelGGL(k_agg_gcn, dim3(Nn / 4), dim3(256), 0, stream, hA, agg, row_ptr, colidx, dinv);
    hipLaunchKernelGGL(k_gemm, dim3(Nn / 32), dim3(256), 0, stream, agg, w4, nil, nil, b4, hA, 0, 1);
    hipLaunchKernelGGL(k_agg_gcn, dim3(Nn / 4), dim3(256), 0, stream, hA, agg, row_ptr, colidx, dinv);
    hipLaunchKernelGGL(k_gemm, dim3(Nn / 32), dim3(256), 0, stream, agg, w5, nil, nil, b5, hA, 0, 0);

    // pool + final linear
    hipLaunchKernelGGL(k_pool, dim3(Nn / 64), dim3(128), 0, stream, hA, batch, emb, gcnt);
    hipLaunchKernelGGL(k_final, dim3(1), dim3(256), 0, stream, emb, gcnt, lw, lb, out);
}

// Round 4
// 709.015 us; speedup vs baseline: 1.1518x; 1.1518x over previous
//
#include <hip/hip_runtime.h>

#define Nn 40000
#define Ee 600000
#define Hh 128
#define Gg 32
#define Cc 6
#define NB 157          // ceil(Nn/256) scan blocks

typedef unsigned int u32;

// ---------------- init ----------------
__global__ __launch_bounds__(256) void k_init(int* counts, float* emb, int* gcnt) {
    int i = blockIdx.x * 256 + threadIdx.x;
    if (i < Nn) counts[i] = 0;
    if (i < Gg * Hh) emb[i] = 0.f;
    if (i < Gg) gcnt[i] = 0;
}

__global__ __launch_bounds__(256) void k_count(const int* __restrict__ dst, int* __restrict__ counts) {
    int i = blockIdx.x * 256 + threadIdx.x;
    if (i < Ee) atomicAdd(&counts[dst[i]], 1);
}

// ---------------- 3-phase multi-block exclusive scan over counts[Nn] ----------------
// phase 1: per-block sums
__global__ __launch_bounds__(256) void k_scan1(const int* __restrict__ counts, int* __restrict__ bsum) {
    __shared__ int sm[256];
    int t = threadIdx.x;
    int i = blockIdx.x * 256 + t;
    sm[t] = (i < Nn) ? counts[i] : 0;
    __syncthreads();
    for (int ofs = 128; ofs > 0; ofs >>= 1) {
        if (t < ofs) sm[t] += sm[t + ofs];
        __syncthreads();
    }
    if (t == 0) bsum[blockIdx.x] = sm[0];
}

// phase 2: scan the NB block sums (one block)
__global__ __launch_bounds__(256) void k_scan2(const int* __restrict__ bsum, int* __restrict__ boff,
                                               int* __restrict__ row_ptr) {
    __shared__ int sm[256];
    int t = threadIdx.x;
    int v = (t < NB) ? bsum[t] : 0;
    sm[t] = v;
    __syncthreads();
    for (int ofs = 1; ofs < 256; ofs <<= 1) {
        int u = (t >= ofs) ? sm[t - ofs] : 0;
        __syncthreads();
        sm[t] += u;
        __syncthreads();
    }
    if (t < NB) boff[t] = sm[t] - v;       // exclusive block offset
    if (t == 255) row_ptr[Nn] = sm[255];   // total = Ee
}

// phase 3: per-block local scan + apply offset; writes row_ptr/cursor/dinv coalesced.
// NOTE: cursor may alias counts — each thread reads counts[i] before writing cursor[i].
__global__ __launch_bounds__(256) void k_scan3(const int* counts, const int* __restrict__ boff,
                                               int* row_ptr, int* cursor, float* dinv) {
    __shared__ int sm[256];
    int t = threadIdx.x;
    int i = blockIdx.x * 256 + t;
    int c = (i < Nn) ? counts[i] : 0;
    sm[t] = c;
    __syncthreads();
    for (int ofs = 1; ofs < 256; ofs <<= 1) {
        int u = (t >= ofs) ? sm[t - ofs] : 0;
        __syncthreads();
        sm[t] += u;
        __syncthreads();
    }
    if (i < Nn) {
        int excl = sm[t] - c + boff[blockIdx.x];
        row_ptr[i] = excl;
        cursor[i] = excl;
        dinv[i] = rsqrtf((float)(c + 1));
    }
}

__global__ __launch_bounds__(256) void k_scatter(const int* __restrict__ src, const int* __restrict__ dst,
                                                 int* __restrict__ cursor, int* __restrict__ colidx) {
    int i = blockIdx.x * 256 + threadIdx.x;
    if (i < Ee) {
        int d = dst[i];
        int p = atomicAdd(&cursor[d], 1);
        if ((u32)p < (u32)Ee) colidx[p] = src[i];
    }
}

// ---------------- aggregations (wave per node), f32 ----------------
__global__ __launch_bounds__(256) void k_agg_plain(const float* __restrict__ in, float* __restrict__ out,
                                                   const int* __restrict__ row_ptr, const int* __restrict__ colidx) {
    int wid = threadIdx.x >> 6, lane = threadIdx.x & 63;
    int node = blockIdx.x * 4 + wid;
    int beg = row_ptr[node], end = row_ptr[node + 1];
    float ax = 0.f, ay = 0.f;
    for (int e = beg; e < end; ++e) {
        int s = colidx[e];
        float2 v = *(const float2*)(in + (size_t)s * 128 + lane * 2);
        ax += v.x; ay += v.y;
    }
    float2 o = { ax, ay };
    *(float2*)(out + (size_t)node * 128 + lane * 2) = o;
}

// GCN normalized aggregation incl. self-loop: out_i = di*sum_s ds*in_s + di^2*in_i
__global__ __launch_bounds__(256) void k_agg_gcn(const float* __restrict__ in, float* __restrict__ out,
                                                 const int* __restrict__ row_ptr, const int* __restrict__ colidx,
                                                 const float* __restrict__ dinv) {
    int wid = threadIdx.x >> 6, lane = threadIdx.x & 63;
    int node = blockIdx.x * 4 + wid;
    int beg = row_ptr[node], end = row_ptr[node + 1];
    float di = dinv[node];
    float ax = 0.f, ay = 0.f;
    for (int e = beg; e < end; ++e) {
        int s = colidx[e];
        float ds = dinv[s];
        float2 v = *(const float2*)(in + (size_t)s * 128 + lane * 2);
        ax += ds * v.x; ay += ds * v.y;
    }
    float2 vs = *(const float2*)(in + (size_t)node * 128 + lane * 2);
    float d2 = di * di;
    float2 o = { di * ax + d2 * vs.x, di * ay + d2 * vs.y };
    *(float2*)(out + (size_t)node * 128 + lane * 2) = o;
}

// ---------------- f32 GEMM: C = [relu]( A1@B1 [+ A2@B2] + bias ), M=40000, K=N=128 ----------------
// Block: 32 rows x 128 cols; B staged in 64 KB LDS; A read as wave-uniform float4 broadcasts.
// C may alias A1 (in-place, layer 2): each block reads only its own 32 rows before writing them.
__global__ __launch_bounds__(256) void k_gemm(const float* A1, const float* __restrict__ B1,
                                              const float* A2, const float* __restrict__ B2,
                                              const float* __restrict__ bias, float* C,
                                              int dual, int relu) {
    __shared__ float Bs[128 * 128];
    int t = threadIdx.x;
    int m0 = blockIdx.x * 32 + (t >> 5) * 4;   // 4 rows per thread
    int n0 = (t & 31) * 4;                     // 4 cols per thread
    float acc[4][4] = {};
    const float* Asrc = A1;
    const float* Bsrc = B1;
    int passes = dual ? 2 : 1;
    for (int pass = 0; pass < passes; ++pass) {
        __syncthreads();
#pragma unroll
        for (int i = 0; i < 16; ++i) {
            int idx = i * 1024 + t * 4;
            *(float4*)&Bs[idx] = *(const float4*)&Bsrc[idx];
        }
        __syncthreads();
        for (int kb = 0; kb < 8; ++kb) {
            float af[4][16];
#pragma unroll
            for (int r = 0; r < 4; ++r)
#pragma unroll
                for (int q = 0; q < 4; ++q)
                    *(float4*)&af[r][q * 4] =
                        *(const float4*)&Asrc[(size_t)(m0 + r) * 128 + kb * 16 + q * 4];
#pragma unroll
            for (int j = 0; j < 16; ++j) {
                float4 b = *(const float4*)&Bs[(kb * 16 + j) * 128 + n0];
#pragma unroll
                for (int r = 0; r < 4; ++r) {
                    acc[r][0] += af[r][j] * b.x;
                    acc[r][1] += af[r][j] * b.y;
                    acc[r][2] += af[r][j] * b.z;
                    acc[r][3] += af[r][j] * b.w;
                }
            }
        }
        Asrc = A2; Bsrc = B2;
    }
#pragma unroll
    for (int r = 0; r < 4; ++r) {
        float4 v;
        float* vp = &v.x;
#pragma unroll
        for (int c = 0; c < 4; ++c) {
            float x = acc[r][c] + bias[n0 + c];
            vp[c] = relu ? fmaxf(x, 0.f) : x;
        }
        *(float4*)&C[(size_t)(m0 + r) * 128 + n0] = v;
    }
}

// ---------------- mean-pool (batch is sorted) ----------------
__global__ __launch_bounds__(128) void k_pool(const float* __restrict__ h, const int* __restrict__ batch,
                                              float* __restrict__ emb, int* __restrict__ gcnt) {
    int f = threadIdx.x;
    int base = blockIdx.x * 64;
    float acc = 0.f; int cnt = 0;
    int curg = batch[base];
    for (int i = 0; i < 64; i++) {
        int node = base + i;
        int g = batch[node];
        if (g != curg) {
            atomicAdd(&emb[curg * 128 + f], acc);
            if (f == 0) atomicAdd(&gcnt[curg], cnt);
            acc = 0.f; cnt = 0; curg = g;
        }
        acc += h[(size_t)node * 128 + f];
        cnt++;
    }
    atomicAdd(&emb[curg * 128 + f], acc);
    if (f == 0) atomicAdd(&gcnt[curg], cnt);
}

// ---------------- final: embedding + logits (f32 out) ----------------
__global__ __launch_bounds__(256) void k_final(const float* __restrict__ emb, const int* __restrict__ gcnt,
                                               const float* __restrict__ lw, const float* __restrict__ lb,
                                               float* __restrict__ out) {
    int t = threadIdx.x;
    for (int i = t; i < Gg * Hh; i += 256) {
        int g = i >> 7;
        float c = fmaxf((float)gcnt[g], 1.f);
        out[Gg * Cc + i] = emb[i] / c;
    }
    if (t < Gg * Cc) {
        int g = t / Cc, c = t % Cc;
        float cn = fmaxf((float)gcnt[g], 1.f);
        float s = lb[c];
        for (int f = 0; f < Hh; f++)
            s += (emb[g * 128 + f] / cn) * lw[f * Cc + c];
        out[t] = s;
    }
}

extern "C" void kernel_launch(void* const* d_in, const int* in_sizes, int n_in,
                              void* d_out, int out_size, void* d_ws, size_t ws_size,
                              hipStream_t stream) {
    const float* x       = (const float*)d_in[0];
    const int*   ei      = (const int*)d_in[1];
    const int*   batch   = (const int*)d_in[2];
    const float* w1_root = (const float*)d_in[3];
    const float* w1_rel  = (const float*)d_in[4];
    const float* b1      = (const float*)d_in[5];
    const float* w2_root = (const float*)d_in[6];
    const float* w2_rel  = (const float*)d_in[7];
    const float* b2      = (const float*)d_in[8];
    const float* w3      = (const float*)d_in[9];
    const float* b3      = (const float*)d_in[10];
    const float* w4      = (const float*)d_in[11];
    const float* b4      = (const float*)d_in[12];
    const float* w5      = (const float*)d_in[13];
    const float* b5      = (const float*)d_in[14];
    const float* lw      = (const float*)d_in[15];
    const float* lb      = (const float*)d_in[16];
    const int* srcp = ei;
    const int* dstp = ei + Ee;
    float* out = (float*)d_out;

    // ---- workspace layout (~44.3 MiB) ----
    char* w = (char*)d_ws;
    size_t off = 0;
    auto alloc = [&](size_t bytes) { size_t r = off; off += (bytes + 255) & ~(size_t)255; return r; };
    int*   counts  = (int*)(w + alloc(Nn * 4));          // doubles as scatter cursor
    int*   row_ptr = (int*)(w + alloc((Nn + 1) * 4));
    int*   colidx  = (int*)(w + alloc((size_t)Ee * 4));
    float* dinv    = (float*)(w + alloc(Nn * 4));
    float* emb     = (float*)(w + alloc(Gg * Hh * 4));
    int*   gcnt    = (int*)(w + alloc(Gg * 4));
    int*   bsum    = (int*)(w + alloc(NB * 4));
    int*   boff    = (int*)(w + alloc(256 * 4));
    float* agg     = (float*)(w + alloc((size_t)Nn * Hh * 4));
    float* hA      = (float*)(w + alloc((size_t)Nn * Hh * 4));
    (void)ws_size;
    const float* nil = (const float*)nullptr;

    // CSR build (multi-block scan)
    hipLaunchKernelGGL(k_init, dim3(157), dim3(256), 0, stream, counts, emb, gcnt);
    hipLaunchKernelGGL(k_count, dim3((Ee + 255) / 256), dim3(256), 0, stream, dstp, counts);
    hipLaunchKernelGGL(k_scan1, dim3(NB), dim3(256), 0, stream, counts, bsum);
    hipLaunchKernelGGL(k_scan2, dim3(1), dim3(256), 0, stream, bsum, boff, row_ptr);
    hipLaunchKernelGGL(k_scan3, dim3(NB), dim3(256), 0, stream, counts, boff, row_ptr, counts /*cursor alias*/, dinv);
    hipLaunchKernelGGL(k_scatter, dim3((Ee + 255) / 256), dim3(256), 0, stream, srcp, dstp, counts, colidx);

    // layer 1 (GraphConv): hA = relu(x@w1_root + agg(x)@w1_rel + b1)
    hipLaunchKernelGGL(k_agg_plain, dim3(Nn / 4), dim3(256), 0, stream, x, agg, row_ptr, colidx);
    hipLaunchKernelGGL(k_gemm, dim3(Nn / 32), dim3(256), 0, stream, x, w1_root, agg, w1_rel, b1, hA, 1, 1);
    // layer 2 (GraphConv), GEMM in-place on hA
    hipLaunchKernelGGL(k_agg_plain, dim3(Nn / 4), dim3(256), 0, stream, hA, agg, row_ptr, colidx);
    hipLaunchKernelGGL(k_gemm, dim3(Nn / 32), dim3(256), 0, stream, hA, w2_root, agg, w2_rel, b2, hA, 1, 1);
    // layers 3..5 (GCNConv): agg = D^-1/2(A+I)D^-1/2 h ; h = [relu](agg@w + b)
    hipLaunchKernelGGL(k_agg_gcn, dim3(Nn / 4), dim3(256), 0, stream, hA, agg, row_ptr, colidx, dinv);
    hipLaunchKernelGGL(k_gemm, dim3(Nn / 32), dim3(256), 0, stream, agg, w3, nil, nil, b3, hA, 0, 1);
    hipLaunchKernelGGL(k_agg_gcn, dim3(Nn / 4), dim3(256), 0, stream, hA, agg, row_ptr, colidx, dinv);
    hipLaunchKernelGGL(k_gemm, dim3(Nn / 32), dim3(256), 0, stream, agg, w4, nil, nil, b4, hA, 0, 1);
    hipLaunchKernelGGL(k_agg_gcn, dim3(Nn / 4), dim3(256), 0, stream, hA, agg, row_ptr, colidx, dinv);
    hipLaunchKernelGGL(k_gemm, dim3(Nn / 32), dim3(256), 0, stream, agg, w5, nil, nil, b5, hA, 0, 0);

    // pool + final linear
    hipLaunchKernelGGL(k_pool, dim3(Nn / 64), dim3(128), 0, stream, hA, batch, emb, gcnt);
    hipLaunchKernelGGL(k_final, dim3(1), dim3(256), 0, stream, emb, gcnt, lw, lb, out);
}

// Round 5
// 413.171 us; speedup vs baseline: 1.9765x; 1.7160x over previous
//
#include <hip/hip_runtime.h>

#define Nn 40000
#define Ee 600000
#define Hh 128
#define Gg 32
#define Cc 6
#define NB 157          // ceil(Nn/256) scan blocks

typedef __bf16 bf16x8 __attribute__((ext_vector_type(8)));
typedef float floatx4 __attribute__((ext_vector_type(4)));
typedef unsigned short u16;
typedef unsigned int u32;

__device__ __forceinline__ float b2f(u32 u) {
    union { u32 i; float f; } v; v.i = u << 16; return v.f;
}
__device__ __forceinline__ u16 f2b(float f) {
    union { float f; u32 i; } v; v.f = f;
    u32 r = v.i + 0x7fffu + ((v.i >> 16) & 1u);   // RNE
    return (u16)(r >> 16);
}

// ---------------- init ----------------
__global__ __launch_bounds__(256) void k_init(int* counts, float* emb, int* gcnt) {
    int i = blockIdx.x * 256 + threadIdx.x;
    if (i < Nn) counts[i] = 0;
    if (i < Gg * Hh) emb[i] = 0.f;
    if (i < Gg) gcnt[i] = 0;
}

__global__ __launch_bounds__(256) void k_count(const int* __restrict__ dst, int* __restrict__ counts) {
    int i = blockIdx.x * 256 + threadIdx.x;
    if (i < Ee) atomicAdd(&counts[dst[i]], 1);
}

// ---------------- 3-phase multi-block exclusive scan ----------------
__global__ __launch_bounds__(256) void k_scan1(const int* __restrict__ counts, int* __restrict__ bsum) {
    __shared__ int sm[256];
    int t = threadIdx.x;
    int i = blockIdx.x * 256 + t;
    sm[t] = (i < Nn) ? counts[i] : 0;
    __syncthreads();
    for (int ofs = 128; ofs > 0; ofs >>= 1) {
        if (t < ofs) sm[t] += sm[t + ofs];
        __syncthreads();
    }
    if (t == 0) bsum[blockIdx.x] = sm[0];
}

__global__ __launch_bounds__(256) void k_scan2(const int* __restrict__ bsum, int* __restrict__ boff,
                                               int* __restrict__ row_ptr) {
    __shared__ int sm[256];
    int t = threadIdx.x;
    int v = (t < NB) ? bsum[t] : 0;
    sm[t] = v;
    __syncthreads();
    for (int ofs = 1; ofs < 256; ofs <<= 1) {
        int u = (t >= ofs) ? sm[t - ofs] : 0;
        __syncthreads();
        sm[t] += u;
        __syncthreads();
    }
    if (t < NB) boff[t] = sm[t] - v;
    if (t == 255) row_ptr[Nn] = sm[255];
}

// cursor may alias counts — each thread reads counts[i] before writing cursor[i].
__global__ __launch_bounds__(256) void k_scan3(const int* counts, const int* __restrict__ boff,
                                               int* row_ptr, int* cursor, float* dinv) {
    __shared__ int sm[256];
    int t = threadIdx.x;
    int i = blockIdx.x * 256 + t;
    int c = (i < Nn) ? counts[i] : 0;
    sm[t] = c;
    __syncthreads();
    for (int ofs = 1; ofs < 256; ofs <<= 1) {
        int u = (t >= ofs) ? sm[t - ofs] : 0;
        __syncthreads();
        sm[t] += u;
        __syncthreads();
    }
    if (i < Nn) {
        int excl = sm[t] - c + boff[blockIdx.x];
        row_ptr[i] = excl;
        cursor[i] = excl;
        dinv[i] = rsqrtf((float)(c + 1));
    }
}

__global__ __launch_bounds__(256) void k_scatter(const int* __restrict__ src, const int* __restrict__ dst,
                                                 int* __restrict__ cursor, int* __restrict__ colidx) {
    int i = blockIdx.x * 256 + threadIdx.x;
    if (i < Ee) {
        int d = dst[i];
        int p = atomicAdd(&cursor[d], 1);
        if ((u32)p < (u32)Ee) colidx[p] = src[i];
    }
}

// ---------------- f32 -> bf16 cast of input features ----------------
__global__ __launch_bounds__(256) void k_cast(const float* __restrict__ x, u16* __restrict__ xb) {
    int i = (blockIdx.x * 256 + threadIdx.x) * 4;   // Nn*Hh = 5.12M, grid covers exactly
    float4 v = *(const float4*)(x + i);
    ushort4 o = { f2b(v.x), f2b(v.y), f2b(v.z), f2b(v.w) };
    *(ushort4*)(xb + i) = o;
}

// ---------------- weight packing: f32 [K=128][N=128] -> bf16 MFMA B-fragment order ----------------
// dst[t*4096 + nt*512 + q*128 + n*8 + j] = w[(t*32+q*8+j)*128 + nt*16+n]
__global__ __launch_bounds__(256) void k_pack(const float* w0, const float* w1, const float* w2,
                                              const float* w3, const float* w4, const float* w5,
                                              const float* w6, u16* dst) {
    int idx = blockIdx.x * 256 + threadIdx.x;
    if (idx >= 7 * 16384) return;
    const float* ws[7] = { w0, w1, w2, w3, w4, w5, w6 };
    int mat = idx >> 14, r = idx & 16383;
    int j = r & 7, n = (r >> 3) & 15, q = (r >> 7) & 3, nt = (r >> 9) & 7, t = r >> 12;
    dst[idx] = f2b(ws[mat][(t * 32 + q * 8 + j) * 128 + nt * 16 + n]);
}

// ---------------- aggregations (wave per node), bf16 rows, f32 accum, 4-deep ILP ----------------
__global__ __launch_bounds__(256) void k_agg_plain(const u16* __restrict__ in, u16* __restrict__ out,
                                                   const int* __restrict__ row_ptr, const int* __restrict__ colidx) {
    int wid = threadIdx.x >> 6, lane = threadIdx.x & 63;
    int node = blockIdx.x * 4 + wid;
    int beg = row_ptr[node], end = row_ptr[node + 1];
    float ax = 0.f, ay = 0.f;
    int e = beg;
    for (; e + 4 <= end; e += 4) {
        int s0 = colidx[e], s1 = colidx[e + 1], s2 = colidx[e + 2], s3 = colidx[e + 3];
        u32 u0 = *(const u32*)(in + (size_t)s0 * 128 + lane * 2);
        u32 u1 = *(const u32*)(in + (size_t)s1 * 128 + lane * 2);
        u32 u2 = *(const u32*)(in + (size_t)s2 * 128 + lane * 2);
        u32 u3 = *(const u32*)(in + (size_t)s3 * 128 + lane * 2);
        ax += b2f(u0 & 0xffff) + b2f(u1 & 0xffff) + b2f(u2 & 0xffff) + b2f(u3 & 0xffff);
        ay += b2f(u0 >> 16) + b2f(u1 >> 16) + b2f(u2 >> 16) + b2f(u3 >> 16);
    }
    for (; e < end; ++e) {
        int s = colidx[e];
        u32 u = *(const u32*)(in + (size_t)s * 128 + lane * 2);
        ax += b2f(u & 0xffff);
        ay += b2f(u >> 16);
    }
    u32 o = (u32)f2b(ax) | ((u32)f2b(ay) << 16);
    *(u32*)(out + (size_t)node * 128 + lane * 2) = o;
}

// GCN: out_i = di*sum_s ds*in_s + di^2*in_i
__global__ __launch_bounds__(256) void k_agg_gcn(const u16* __restrict__ in, u16* __restrict__ out,
                                                 const int* __restrict__ row_ptr, const int* __restrict__ colidx,
                                                 const float* __restrict__ dinv) {
    int wid = threadIdx.x >> 6, lane = threadIdx.x & 63;
    int node = blockIdx.x * 4 + wid;
    int beg = row_ptr[node], end = row_ptr[node + 1];
    float di = dinv[node];
    float ax = 0.f, ay = 0.f;
    int e = beg;
    for (; e + 4 <= end; e += 4) {
        int s0 = colidx[e], s1 = colidx[e + 1], s2 = colidx[e + 2], s3 = colidx[e + 3];
        float d0 = dinv[s0], d1 = dinv[s1], d2 = dinv[s2], d3 = dinv[s3];
        u32 u0 = *(const u32*)(in + (size_t)s0 * 128 + lane * 2);
        u32 u1 = *(const u32*)(in + (size_t)s1 * 128 + lane * 2);
        u32 u2 = *(const u32*)(in + (size_t)s2 * 128 + lane * 2);
        u32 u3 = *(const u32*)(in + (size_t)s3 * 128 + lane * 2);
        ax += d0 * b2f(u0 & 0xffff) + d1 * b2f(u1 & 0xffff) + d2 * b2f(u2 & 0xffff) + d3 * b2f(u3 & 0xffff);
        ay += d0 * b2f(u0 >> 16) + d1 * b2f(u1 >> 16) + d2 * b2f(u2 >> 16) + d3 * b2f(u3 >> 16);
    }
    for (; e < end; ++e) {
        int s = colidx[e];
        float ds = dinv[s];
        u32 u = *(const u32*)(in + (size_t)s * 128 + lane * 2);
        ax += ds * b2f(u & 0xffff);
        ay += ds * b2f(u >> 16);
    }
    u32 us = *(const u32*)(in + (size_t)node * 128 + lane * 2);
    float d2n = di * di;
    ax = di * ax + d2n * b2f(us & 0xffff);
    ay = di * ay + d2n * b2f(us >> 16);
    u32 o = (u32)f2b(ax) | ((u32)f2b(ay) << 16);
    *(u32*)(out + (size_t)node * 128 + lane * 2) = o;
}

// ---------------- MFMA GEMM: C = [relu]( A1@B1 [+ A2@B2] + bias ), M=40000, K=N=128, bf16 in/out ----------------
// wave per 16-row m-tile. C may alias A1 (each wave touches only its own rows). f32 bias.
__global__ __launch_bounds__(256) void k_gemm(const u16* A1, const u16* __restrict__ Bp1,
                                              const u16* A2, const u16* __restrict__ Bp2,
                                              const float* __restrict__ bias, u16* C,
                                              int dual, int relu) {
    int wid = threadIdx.x >> 6, lane = threadIdx.x & 63;
    int m0 = (blockIdx.x * 4 + wid) * 16;
    int n = lane & 15, q = lane >> 4;
    floatx4 acc[8];
#pragma unroll
    for (int i = 0; i < 8; i++) acc[i] = (floatx4){0.f, 0.f, 0.f, 0.f};

    const u16* arow = A1 + (size_t)(m0 + n) * 128 + q * 8;
#pragma unroll
    for (int t = 0; t < 4; t++) {
        bf16x8 a = *(const bf16x8*)(arow + t * 32);
        const u16* bp = Bp1 + t * 4096 + q * 128 + n * 8;
#pragma unroll
        for (int nt = 0; nt < 8; nt++) {
            bf16x8 b = *(const bf16x8*)(bp + nt * 512);
            acc[nt] = __builtin_amdgcn_mfma_f32_16x16x32_bf16(a, b, acc[nt], 0, 0, 0);
        }
    }
    if (dual) {
        const u16* arow2 = A2 + (size_t)(m0 + n) * 128 + q * 8;
#pragma unroll
        for (int t = 0; t < 4; t++) {
            bf16x8 a = *(const bf16x8*)(arow2 + t * 32);
            const u16* bp = Bp2 + t * 4096 + q * 128 + n * 8;
#pragma unroll
            for (int nt = 0; nt < 8; nt++) {
                bf16x8 b = *(const bf16x8*)(bp + nt * 512);
                acc[nt] = __builtin_amdgcn_mfma_f32_16x16x32_bf16(a, b, acc[nt], 0, 0, 0);
            }
        }
    }
    // D: row = q*4 + r, col = nt*16 + n  (m89-verified)
#pragma unroll
    for (int nt = 0; nt < 8; nt++) {
        int col = nt * 16 + n;
        float bv = bias[col];
#pragma unroll
        for (int r = 0; r < 4; r++) {
            float v = acc[nt][r] + bv;
            if (relu) v = fmaxf(v, 0.f);
            C[(size_t)(m0 + q * 4 + r) * 128 + col] = f2b(v);
        }
    }
}

// ---------------- mean-pool (batch is sorted), bf16 in, f32 accum ----------------
__global__ __launch_bounds__(128) void k_pool(const u16* __restrict__ h, const int* __restrict__ batch,
                                              float* __restrict__ emb, int* __restrict__ gcnt) {
    int f = threadIdx.x;
    int base = blockIdx.x * 64;
    float acc = 0.f; int cnt = 0;
    int curg = batch[base];
    for (int i = 0; i < 64; i++) {
        int node = base + i;
        int g = batch[node];
        if (g != curg) {
            atomicAdd(&emb[curg * 128 + f], acc);
            if (f == 0) atomicAdd(&gcnt[curg], cnt);
            acc = 0.f; cnt = 0; curg = g;
        }
        acc += b2f((u32)h[(size_t)node * 128 + f]);
        cnt++;
    }
    atomicAdd(&emb[curg * 128 + f], acc);
    if (f == 0) atomicAdd(&gcnt[curg], cnt);
}

// ---------------- final: embedding + logits (f32 out) ----------------
__global__ __launch_bounds__(256) void k_final(const float* __restrict__ emb, const int* __restrict__ gcnt,
                                               const float* __restrict__ lw, const float* __restrict__ lb,
                                               float* __restrict__ out) {
    int t = threadIdx.x;
    for (int i = t; i < Gg * Hh; i += 256) {
        int g = i >> 7;
        float c = fmaxf((float)gcnt[g], 1.f);
        out[Gg * Cc + i] = emb[i] / c;
    }
    if (t < Gg * Cc) {
        int g = t / Cc, c = t % Cc;
        float cn = fmaxf((float)gcnt[g], 1.f);
        float s = lb[c];
        for (int f = 0; f < Hh; f++)
            s += (emb[g * 128 + f] / cn) * lw[f * Cc + c];
        out[t] = s;
    }
}

extern "C" void kernel_launch(void* const* d_in, const int* in_sizes, int n_in,
                              void* d_out, int out_size, void* d_ws, size_t ws_size,
                              hipStream_t stream) {
    const float* x       = (const float*)d_in[0];
    const int*   ei      = (const int*)d_in[1];
    const int*   batch   = (const int*)d_in[2];
    const float* w1_root = (const float*)d_in[3];
    const float* w1_rel  = (const float*)d_in[4];
    const float* b1      = (const float*)d_in[5];
    const float* w2_root = (const float*)d_in[6];
    const float* w2_rel  = (const float*)d_in[7];
    const float* b2      = (const float*)d_in[8];
    const float* w3      = (const float*)d_in[9];
    const float* b3      = (const float*)d_in[10];
    const float* w4      = (const float*)d_in[11];
    const float* b4      = (const float*)d_in[12];
    const float* w5      = (const float*)d_in[13];
    const float* b5      = (const float*)d_in[14];
    const float* lw      = (const float*)d_in[15];
    const float* lb      = (const float*)d_in[16];
    const int* srcp = ei;
    const int* dstp = ei + Ee;
    float* out = (float*)d_out;

    // ---- workspace (~34 MiB) ----
    char* w = (char*)d_ws;
    size_t off = 0;
    auto alloc = [&](size_t bytes) { size_t r = off; off += (bytes + 255) & ~(size_t)255; return r; };
    int*   counts  = (int*)(w + alloc(Nn * 4));          // doubles as scatter cursor
    int*   row_ptr = (int*)(w + alloc((Nn + 1) * 4));
    int*   colidx  = (int*)(w + alloc((size_t)Ee * 4));
    float* dinv    = (float*)(w + alloc(Nn * 4));
    float* emb     = (float*)(w + alloc(Gg * Hh * 4));
    int*   gcnt    = (int*)(w + alloc(Gg * 4));
    int*   bsum    = (int*)(w + alloc(NB * 4));
    int*   boff    = (int*)(w + alloc(256 * 4));
    u16*   pw      = (u16*)(w + alloc(7 * 16384 * 2));
    u16*   xb      = (u16*)(w + alloc((size_t)Nn * Hh * 2));
    u16*   agg     = (u16*)(w + alloc((size_t)Nn * Hh * 2));
    u16*   hA      = (u16*)(w + alloc((size_t)Nn * Hh * 2));
    (void)ws_size;

    u16* pw1r = pw + 0 * 16384;
    u16* pw1l = pw + 1 * 16384;
    u16* pw2r = pw + 2 * 16384;
    u16* pw2l = pw + 3 * 16384;
    u16* pw3  = pw + 4 * 16384;
    u16* pw4  = pw + 5 * 16384;
    u16* pw5  = pw + 6 * 16384;
    const u16* nil = (const u16*)nullptr;

    // CSR build + casts/packs
    hipLaunchKernelGGL(k_init, dim3(157), dim3(256), 0, stream, counts, emb, gcnt);
    hipLaunchKernelGGL(k_count, dim3((Ee + 255) / 256), dim3(256), 0, stream, dstp, counts);
    hipLaunchKernelGGL(k_scan1, dim3(NB), dim3(256), 0, stream, counts, bsum);
    hipLaunchKernelGGL(k_scan2, dim3(1), dim3(256), 0, stream, bsum, boff, row_ptr);
    hipLaunchKernelGGL(k_scan3, dim3(NB), dim3(256), 0, stream, counts, boff, row_ptr, counts, dinv);
    hipLaunchKernelGGL(k_scatter, dim3((Ee + 255) / 256), dim3(256), 0, stream, srcp, dstp, counts, colidx);
    hipLaunchKernelGGL(k_cast, dim3(Nn * Hh / 1024), dim3(256), 0, stream, x, xb);
    hipLaunchKernelGGL(k_pack, dim3((7 * 16384 + 255) / 256), dim3(256), 0, stream,
                       w1_root, w1_rel, w2_root, w2_rel, w3, w4, w5, pw);

    // layer 1 (GraphConv): hA = relu(xb@w1_root + agg(xb)@w1_rel + b1)
    hipLaunchKernelGGL(k_agg_plain, dim3(Nn / 4), dim3(256), 0, stream, xb, agg, row_ptr, colidx);
    hipLaunchKernelGGL(k_gemm, dim3(Nn / 64), dim3(256), 0, stream, xb, pw1r, agg, pw1l, b1, hA, 1, 1);
    // layer 2 (GraphConv), GEMM in-place on hA
    hipLaunchKernelGGL(k_agg_plain, dim3(Nn / 4), dim3(256), 0, stream, hA, agg, row_ptr, colidx);
    hipLaunchKernelGGL(k_gemm, dim3(Nn / 64), dim3(256), 0, stream, hA, pw2r, agg, pw2l, b2, hA, 1, 1);
    // layers 3..5 (GCNConv): agg = D^-1/2(A+I)D^-1/2 h ; h = [relu](agg@w + b)
    hipLaunchKernelGGL(k_agg_gcn, dim3(Nn / 4), dim3(256), 0, stream, hA, agg, row_ptr, colidx, dinv);
    hipLaunchKernelGGL(k_gemm, dim3(Nn / 64), dim3(256), 0, stream, agg, pw3, nil, nil, b3, hA, 0, 1);
    hipLaunchKernelGGL(k_agg_gcn, dim3(Nn / 4), dim3(256), 0, stream, hA, agg, row_ptr, colidx, dinv);
    hipLaunchKernelGGL(k_gemm, dim3(Nn / 64), dim3(256), 0, stream, agg, pw4, nil, nil, b4, hA, 0, 1);
    hipLaunchKernelGGL(k_agg_gcn, dim3(Nn / 4), dim3(256), 0, stream, hA, agg, row_ptr, colidx, dinv);
    hipLaunchKernelGGL(k_gemm, dim3(Nn / 64), dim3(256), 0, stream, agg, pw5, nil, nil, b5, hA, 0, 0);

    // pool + final linear
    hipLaunchKernelGGL(k_pool, dim3(Nn / 64), dim3(128), 0, stream, hA, batch, emb, gcnt);
    hipLaunchKernelGGL(k_final, dim3(1), dim3(256), 0, stream, emb, gcnt, lw, lb, out);
}

// Round 7
// 376.504 us; speedup vs baseline: 2.1690x; 1.0974x over previous
//
#include <hip/hip_runtime.h>

#define Nn 40000
#define Ee 600000
#define Hh 128
#define Gg 32
#define Cc 6
#define NB 157          // ceil(Nn/256) scan blocks

typedef __bf16 bf16x8 __attribute__((ext_vector_type(8)));
typedef float floatx4 __attribute__((ext_vector_type(4)));
typedef unsigned short u16;
typedef unsigned int u32;

__device__ __forceinline__ float b2f(u32 u) {
    union { u32 i; float f; } v; v.i = u << 16; return v.f;
}
__device__ __forceinline__ float b2f_hi(u32 u) {
    union { u32 i; float f; } v; v.i = u & 0xffff0000u; return v.f;
}
__device__ __forceinline__ u16 f2b(float f) {
    union { float f; u32 i; } v; v.f = f;
    u32 r = v.i + 0x7fffu + ((v.i >> 16) & 1u);   // RNE
    return (u16)(r >> 16);
}

// ---------------- init ----------------
__global__ __launch_bounds__(256) void k_init(int* counts, float* emb, int* gcnt) {
    int i = blockIdx.x * 256 + threadIdx.x;
    if (i < Nn) counts[i] = 0;
    if (i < Gg * Hh) emb[i] = 0.f;
    if (i < Gg) gcnt[i] = 0;
}

__global__ __launch_bounds__(256) void k_count(const int* __restrict__ dst, int* __restrict__ counts) {
    int i = blockIdx.x * 256 + threadIdx.x;
    if (i < Ee) atomicAdd(&counts[dst[i]], 1);
}

// ---------------- 3-phase multi-block exclusive scan ----------------
__global__ __launch_bounds__(256) void k_scan1(const int* __restrict__ counts, int* __restrict__ bsum) {
    __shared__ int sm[256];
    int t = threadIdx.x;
    int i = blockIdx.x * 256 + t;
    sm[t] = (i < Nn) ? counts[i] : 0;
    __syncthreads();
    for (int ofs = 128; ofs > 0; ofs >>= 1) {
        if (t < ofs) sm[t] += sm[t + ofs];
        __syncthreads();
    }
    if (t == 0) bsum[blockIdx.x] = sm[0];
}

__global__ __launch_bounds__(256) void k_scan2(const int* __restrict__ bsum, int* __restrict__ boff,
                                               int* __restrict__ row_ptr) {
    __shared__ int sm[256];
    int t = threadIdx.x;
    int v = (t < NB) ? bsum[t] : 0;
    sm[t] = v;
    __syncthreads();
    for (int ofs = 1; ofs < 256; ofs <<= 1) {
        int u = (t >= ofs) ? sm[t - ofs] : 0;
        __syncthreads();
        sm[t] += u;
        __syncthreads();
    }
    if (t < NB) boff[t] = sm[t] - v;
    if (t == 255) row_ptr[Nn] = sm[255];
}

// cursor may alias counts — each thread reads counts[i] before writing cursor[i].
__global__ __launch_bounds__(256) void k_scan3(const int* counts, const int* __restrict__ boff,
                                               int* row_ptr, int* cursor, float* dinv) {
    __shared__ int sm[256];
    int t = threadIdx.x;
    int i = blockIdx.x * 256 + t;
    int c = (i < Nn) ? counts[i] : 0;
    sm[t] = c;
    __syncthreads();
    for (int ofs = 1; ofs < 256; ofs <<= 1) {
        int u = (t >= ofs) ? sm[t - ofs] : 0;
        __syncthreads();
        sm[t] += u;
        __syncthreads();
    }
    if (i < Nn) {
        int excl = sm[t] - c + boff[blockIdx.x];
        row_ptr[i] = excl;
        cursor[i] = excl;
        dinv[i] = rsqrtf((float)(c + 1));
    }
}

__global__ __launch_bounds__(256) void k_scatter(const int* __restrict__ src, const int* __restrict__ dst,
                                                 int* __restrict__ cursor, int* __restrict__ colidx) {
    int i = blockIdx.x * 256 + threadIdx.x;
    if (i < Ee) {
        int d = dst[i];
        int p = atomicAdd(&cursor[d], 1);
        if ((u32)p < (u32)Ee) colidx[p] = src[i];
    }
}

// ---------------- f32 -> bf16 cast of input features ----------------
__global__ __launch_bounds__(256) void k_cast(const float* __restrict__ x, u16* __restrict__ xb) {
    int i = (blockIdx.x * 256 + threadIdx.x) * 4;
    float4 v = *(const float4*)(x + i);
    ushort4 o = { f2b(v.x), f2b(v.y), f2b(v.z), f2b(v.w) };
    *(ushort4*)(xb + i) = o;
}

// ---------------- weight packing: f32 [K=128][N=128] -> bf16 MFMA B-fragment order ----------------
__global__ __launch_bounds__(256) void k_pack(const float* w0, const float* w1, const float* w2,
                                              const float* w3, const float* w4, const float* w5,
                                              const float* w6, u16* dst) {
    int idx = blockIdx.x * 256 + threadIdx.x;
    if (idx >= 7 * 16384) return;
    const float* ws[7] = { w0, w1, w2, w3, w4, w5, w6 };
    int mat = idx >> 14, r = idx & 16383;
    int j = r & 7, n = (r >> 3) & 15, q = (r >> 7) & 3, nt = (r >> 9) & 7, t = r >> 12;
    dst[idx] = f2b(ws[mat][(t * 32 + q * 8 + j) * 128 + nt * 16 + n]);
}

// ---------------- aggregations: 4 nodes/wave, 16 lanes/node, dwordx4 per lane ----------------
// NOTE: macro param must NOT be named 'w' — member access .w would be substituted too.
#define UNPACK_ADD(V)                                   \
    acc0 += b2f((V).x);  acc1 += b2f_hi((V).x);         \
    acc2 += b2f((V).y);  acc3 += b2f_hi((V).y);         \
    acc4 += b2f((V).z);  acc5 += b2f_hi((V).z);         \
    acc6 += b2f((V).w);  acc7 += b2f_hi((V).w);

#define UNPACK_FMA(V, d)                                      \
    acc0 += (d) * b2f((V).x);  acc1 += (d) * b2f_hi((V).x);   \
    acc2 += (d) * b2f((V).y);  acc3 += (d) * b2f_hi((V).y);   \
    acc4 += (d) * b2f((V).z);  acc5 += (d) * b2f_hi((V).z);   \
    acc6 += (d) * b2f((V).w);  acc7 += (d) * b2f_hi((V).w);

__global__ __launch_bounds__(256) void k_agg_plain(const u16* __restrict__ in, u16* __restrict__ out,
                                                   const int* __restrict__ row_ptr, const int* __restrict__ colidx) {
    int wave = threadIdx.x >> 6, lane = threadIdx.x & 63;
    int g = lane >> 4, l = lane & 15;
    int node = (blockIdx.x * 4 + wave) * 4 + g;     // 16 nodes per block
    int beg = row_ptr[node], end = row_ptr[node + 1];
    float acc0 = 0.f, acc1 = 0.f, acc2 = 0.f, acc3 = 0.f,
          acc4 = 0.f, acc5 = 0.f, acc6 = 0.f, acc7 = 0.f;
    const u16* base = in + l * 8;                   // this lane's 16-B slice of every row
    int e = beg;
    for (; e + 4 <= end; e += 4) {
        int s0 = colidx[e], s1 = colidx[e + 1], s2 = colidx[e + 2], s3 = colidx[e + 3];
        uint4 v0 = *(const uint4*)(base + (size_t)s0 * 128);
        uint4 v1 = *(const uint4*)(base + (size_t)s1 * 128);
        uint4 v2 = *(const uint4*)(base + (size_t)s2 * 128);
        uint4 v3 = *(const uint4*)(base + (size_t)s3 * 128);
        UNPACK_ADD(v0) UNPACK_ADD(v1) UNPACK_ADD(v2) UNPACK_ADD(v3)
    }
    for (; e < end; ++e) {
        uint4 v0 = *(const uint4*)(base + (size_t)colidx[e] * 128);
        UNPACK_ADD(v0)
    }
    uint4 o;
    o.x = (u32)f2b(acc0) | ((u32)f2b(acc1) << 16);
    o.y = (u32)f2b(acc2) | ((u32)f2b(acc3) << 16);
    o.z = (u32)f2b(acc4) | ((u32)f2b(acc5) << 16);
    o.w = (u32)f2b(acc6) | ((u32)f2b(acc7) << 16);
    *(uint4*)(out + (size_t)node * 128 + l * 8) = o;
}

// GCN: out_i = di*sum_s ds*in_s + di^2*in_i
__global__ __launch_bounds__(256) void k_agg_gcn(const u16* __restrict__ in, u16* __restrict__ out,
                                                 const int* __restrict__ row_ptr, const int* __restrict__ colidx,
                                                 const float* __restrict__ dinv) {
    int wave = threadIdx.x >> 6, lane = threadIdx.x & 63;
    int g = lane >> 4, l = lane & 15;
    int node = (blockIdx.x * 4 + wave) * 4 + g;
    int beg = row_ptr[node], end = row_ptr[node + 1];
    float di = dinv[node];
    float acc0 = 0.f, acc1 = 0.f, acc2 = 0.f, acc3 = 0.f,
          acc4 = 0.f, acc5 = 0.f, acc6 = 0.f, acc7 = 0.f;
    const u16* base = in + l * 8;
    int e = beg;
    for (; e + 4 <= end; e += 4) {
        int s0 = colidx[e], s1 = colidx[e + 1], s2 = colidx[e + 2], s3 = colidx[e + 3];
        float d0 = dinv[s0], d1 = dinv[s1], d2 = dinv[s2], d3 = dinv[s3];
        uint4 v0 = *(const uint4*)(base + (size_t)s0 * 128);
        uint4 v1 = *(const uint4*)(base + (size_t)s1 * 128);
        uint4 v2 = *(const uint4*)(base + (size_t)s2 * 128);
        uint4 v3 = *(const uint4*)(base + (size_t)s3 * 128);
        UNPACK_FMA(v0, d0) UNPACK_FMA(v1, d1) UNPACK_FMA(v2, d2) UNPACK_FMA(v3, d3)
    }
    for (; e < end; ++e) {
        int s = colidx[e];
        float ds = dinv[s];
        uint4 v0 = *(const uint4*)(base + (size_t)s * 128);
        UNPACK_FMA(v0, ds)
    }
    uint4 us = *(const uint4*)(in + (size_t)node * 128 + l * 8);
    float d2n = di * di;
    acc0 = di * acc0 + d2n * b2f(us.x);  acc1 = di * acc1 + d2n * b2f_hi(us.x);
    acc2 = di * acc2 + d2n * b2f(us.y);  acc3 = di * acc3 + d2n * b2f_hi(us.y);
    acc4 = di * acc4 + d2n * b2f(us.z);  acc5 = di * acc5 + d2n * b2f_hi(us.z);
    acc6 = di * acc6 + d2n * b2f(us.w);  acc7 = di * acc7 + d2n * b2f_hi(us.w);
    uint4 o;
    o.x = (u32)f2b(acc0) | ((u32)f2b(acc1) << 16);
    o.y = (u32)f2b(acc2) | ((u32)f2b(acc3) << 16);
    o.z = (u32)f2b(acc4) | ((u32)f2b(acc5) << 16);
    o.w = (u32)f2b(acc6) | ((u32)f2b(acc7) << 16);
    *(uint4*)(out + (size_t)node * 128 + l * 8) = o;
}

// ---------------- MFMA GEMM: C = [relu]( A1@B1 [+ A2@B2] + bias ), M=40000, K=N=128, bf16 in/out ----------------
__global__ __launch_bounds__(256) void k_gemm(const u16* A1, const u16* __restrict__ Bp1,
                                              const u16* A2, const u16* __restrict__ Bp2,
                                              const float* __restrict__ bias, u16* C,
                                              int dual, int relu) {
    int wid = threadIdx.x >> 6, lane = threadIdx.x & 63;
    int m0 = (blockIdx.x * 4 + wid) * 16;
    int n = lane & 15, q = lane >> 4;
    floatx4 acc[8];
#pragma unroll
    for (int i = 0; i < 8; i++) acc[i] = (floatx4){0.f, 0.f, 0.f, 0.f};

    const u16* arow = A1 + (size_t)(m0 + n) * 128 + q * 8;
#pragma unroll
    for (int t = 0; t < 4; t++) {
        bf16x8 a = *(const bf16x8*)(arow + t * 32);
        const u16* bp = Bp1 + t * 4096 + q * 128 + n * 8;
#pragma unroll
        for (int nt = 0; nt < 8; nt++) {
            bf16x8 b = *(const bf16x8*)(bp + nt * 512);
            acc[nt] = __builtin_amdgcn_mfma_f32_16x16x32_bf16(a, b, acc[nt], 0, 0, 0);
        }
    }
    if (dual) {
        const u16* arow2 = A2 + (size_t)(m0 + n) * 128 + q * 8;
#pragma unroll
        for (int t = 0; t < 4; t++) {
            bf16x8 a = *(const bf16x8*)(arow2 + t * 32);
            const u16* bp = Bp2 + t * 4096 + q * 128 + n * 8;
#pragma unroll
            for (int nt = 0; nt < 8; nt++) {
                bf16x8 b = *(const bf16x8*)(bp + nt * 512);
                acc[nt] = __builtin_amdgcn_mfma_f32_16x16x32_bf16(a, b, acc[nt], 0, 0, 0);
            }
        }
    }
#pragma unroll
    for (int nt = 0; nt < 8; nt++) {
        int col = nt * 16 + n;
        float bv = bias[col];
#pragma unroll
        for (int r = 0; r < 4; r++) {
            float v = acc[nt][r] + bv;
            if (relu) v = fmaxf(v, 0.f);
            C[(size_t)(m0 + q * 4 + r) * 128 + col] = f2b(v);
        }
    }
}

// ---------------- mean-pool (batch is sorted), bf16 in, f32 accum ----------------
__global__ __launch_bounds__(128) void k_pool(const u16* __restrict__ h, const int* __restrict__ batch,
                                              float* __restrict__ emb, int* __restrict__ gcnt) {
    int f = threadIdx.x;
    int base = blockIdx.x * 64;
    float acc = 0.f; int cnt = 0;
    int curg = batch[base];
    for (int i = 0; i < 64; i++) {
        int node = base + i;
        int g = batch[node];
        if (g != curg) {
            atomicAdd(&emb[curg * 128 + f], acc);
            if (f == 0) atomicAdd(&gcnt[curg], cnt);
            acc = 0.f; cnt = 0; curg = g;
        }
        acc += b2f((u32)h[(size_t)node * 128 + f]);
        cnt++;
    }
    atomicAdd(&emb[curg * 128 + f], acc);
    if (f == 0) atomicAdd(&gcnt[curg], cnt);
}

// ---------------- final: embedding + logits (f32 out) ----------------
__global__ __launch_bounds__(256) void k_final(const float* __restrict__ emb, const int* __restrict__ gcnt,
                                               const float* __restrict__ lw, const float* __restrict__ lb,
                                               float* __restrict__ out) {
    int t = threadIdx.x;
    for (int i = t; i < Gg * Hh; i += 256) {
        int g = i >> 7;
        float c = fmaxf((float)gcnt[g], 1.f);
        out[Gg * Cc + i] = emb[i] / c;
    }
    if (t < Gg * Cc) {
        int g = t / Cc, c = t % Cc;
        float cn = fmaxf((float)gcnt[g], 1.f);
        float s = lb[c];
        for (int f = 0; f < Hh; f++)
            s += (emb[g * 128 + f] / cn) * lw[f * Cc + c];
        out[t] = s;
    }
}

extern "C" void kernel_launch(void* const* d_in, const int* in_sizes, int n_in,
                              void* d_out, int out_size, void* d_ws, size_t ws_size,
                              hipStream_t stream) {
    const float* x       = (const float*)d_in[0];
    const int*   ei      = (const int*)d_in[1];
    const int*   batch   = (const int*)d_in[2];
    const float* w1_root = (const float*)d_in[3];
    const float* w1_rel  = (const float*)d_in[4];
    const float* b1      = (const float*)d_in[5];
    const float* w2_root = (const float*)d_in[6];
    const float* w2_rel  = (const float*)d_in[7];
    const float* b2      = (const float*)d_in[8];
    const float* w3      = (const float*)d_in[9];
    const float* b3      = (const float*)d_in[10];
    const float* w4      = (const float*)d_in[11];
    const float* b4      = (const float*)d_in[12];
    const float* w5      = (const float*)d_in[13];
    const float* b5      = (const float*)d_in[14];
    const float* lw      = (const float*)d_in[15];
    const float* lb      = (const float*)d_in[16];
    const int* srcp = ei;
    const int* dstp = ei + Ee;
    float* out = (float*)d_out;

    char* w = (char*)d_ws;
    size_t off = 0;
    auto alloc = [&](size_t bytes) { size_t r = off; off += (bytes + 255) & ~(size_t)255; return r; };
    int*   counts  = (int*)(w + alloc(Nn * 4));          // doubles as scatter cursor
    int*   row_ptr = (int*)(w + alloc((Nn + 1) * 4));
    int*   colidx  = (int*)(w + alloc((size_t)Ee * 4));
    float* dinv    = (float*)(w + alloc(Nn * 4));
    float* emb     = (float*)(w + alloc(Gg * Hh * 4));
    int*   gcnt    = (int*)(w + alloc(Gg * 4));
    int*   bsum    = (int*)(w + alloc(NB * 4));
    int*   boff    = (int*)(w + alloc(256 * 4));
    u16*   pw      = (u16*)(w + alloc(7 * 16384 * 2));
    u16*   xb      = (u16*)(w + alloc((size_t)Nn * Hh * 2));
    u16*   agg     = (u16*)(w + alloc((size_t)Nn * Hh * 2));
    u16*   hA      = (u16*)(w + alloc((size_t)Nn * Hh * 2));
    (void)ws_size;

    u16* pw1r = pw + 0 * 16384;
    u16* pw1l = pw + 1 * 16384;
    u16* pw2r = pw + 2 * 16384;
    u16* pw2l = pw + 3 * 16384;
    u16* pw3  = pw + 4 * 16384;
    u16* pw4  = pw + 5 * 16384;
    u16* pw5  = pw + 6 * 16384;
    const u16* nil = (const u16*)nullptr;

    // CSR build + casts/packs
    hipLaunchKernelGGL(k_init, dim3(157), dim3(256), 0, stream, counts, emb, gcnt);
    hipLaunchKernelGGL(k_count, dim3((Ee + 255) / 256), dim3(256), 0, stream, dstp, counts);
    hipLaunchKernelGGL(k_scan1, dim3(NB), dim3(256), 0, stream, counts, bsum);
    hipLaunchKernelGGL(k_scan2, dim3(1), dim3(256), 0, stream, bsum, boff, row_ptr);
    hipLaunchKernelGGL(k_scan3, dim3(NB), dim3(256), 0, stream, counts, boff, row_ptr, counts, dinv);
    hipLaunchKernelGGL(k_scatter, dim3((Ee + 255) / 256), dim3(256), 0, stream, srcp, dstp, counts, colidx);
    hipLaunchKernelGGL(k_cast, dim3(Nn * Hh / 1024), dim3(256), 0, stream, x, xb);
    hipLaunchKernelGGL(k_pack, dim3((7 * 16384 + 255) / 256), dim3(256), 0, stream,
                       w1_root, w1_rel, w2_root, w2_rel, w3, w4, w5, pw);

    // layer 1 (GraphConv): hA = relu(xb@w1_root + agg(xb)@w1_rel + b1)
    hipLaunchKernelGGL(k_agg_plain, dim3(Nn / 16), dim3(256), 0, stream, xb, agg, row_ptr, colidx);
    hipLaunchKernelGGL(k_gemm, dim3(Nn / 64), dim3(256), 0, stream, xb, pw1r, agg, pw1l, b1, hA, 1, 1);
    // layer 2 (GraphConv), GEMM in-place on hA
    hipLaunchKernelGGL(k_agg_plain, dim3(Nn / 16), dim3(256), 0, stream, hA, agg, row_ptr, colidx);
    hipLaunchKernelGGL(k_gemm, dim3(Nn / 64), dim3(256), 0, stream, hA, pw2r, agg, pw2l, b2, hA, 1, 1);
    // layers 3..5 (GCNConv)
    hipLaunchKernelGGL(k_agg_gcn, dim3(Nn / 16), dim3(256), 0, stream, hA, agg, row_ptr, colidx, dinv);
    hipLaunchKernelGGL(k_gemm, dim3(Nn / 64), dim3(256), 0, stream, agg, pw3, nil, nil, b3, hA, 0, 1);
    hipLaunchKernelGGL(k_agg_gcn, dim3(Nn / 16), dim3(256), 0, stream, hA, agg, row_ptr, colidx, dinv);
    hipLaunchKernelGGL(k_gemm, dim3(Nn / 64), dim3(256), 0, stream, agg, pw4, nil, nil, b4, hA, 0, 1);
    hipLaunchKernelGGL(k_agg_gcn, dim3(Nn / 16), dim3(256), 0, stream, hA, agg, row_ptr, colidx, dinv);
    hipLaunchKernelGGL(k_gemm, dim3(Nn / 64), dim3(256), 0, stream, agg, pw5, nil, nil, b5, hA, 0, 0);

    // pool + final linear
    hipLaunchKernelGGL(k_pool, dim3(Nn / 64), dim3(128), 0, stream, hA, batch, emb, gcnt);
    hipLaunchKernelGGL(k_final, dim3(1), dim3(256), 0, stream, emb, gcnt, lw, lb, out);
}